// Round 1
// baseline (93.620 us; speedup 1.0000x reference)
//
#include <hip/hip_runtime.h>

// ThinPlateSpline: out = K_query @ rbf_weights + P_query @ poly_coeffs
//   K_ij = r*ln(r), r = ||u_i - c_j|| (d=3)
//   kk = sqrt(r2) * log2(r2) * C, C = 0.5*ln2 folded into staged weights.
//
// R14: R13 was transcendental-bound: 8 v_sqrt/v_log per j-wave at ~32cyc each
// = ~256 of ~288 cyc/iter (fits measured ~33us kernel; bench total also
// carries a ~41us harness 256MiB poison fill we cannot touch). This round
// evicts BOTH trans ops onto the full-rate packed-FP32 pipe:
//   sqrt:  magic rsqrt seed (0x5f3759df - b>>1) + 2 packed Newton + r2*x
//          (rel err ~5e-6)
//   log2:  z = cvt_f32_u32(bits)*2^-23 - 127 = e + t EXACT, plus deg-6
//          poly h(t)=log2(1+t)-t on t in [0,1) (Chebyshev-derived, ~3e-6)
// New loop = ~33 packed/int VALU instrs per 2-pair group (~0.52 cyc/pair vs
// ~1.13). Predicted kernel ~16-19us, bench ~61-64us. Launch bounds relaxed
// 8->4 waves/EU (extra temps + hoisted coeffs; LDS still allows 8 blk/CU).
// Structure otherwise = R13: BLK=256 (4 waves = 4 n-splits), JCHUNK=128,
// grid (64,32), pre-duplicated packed LDS records, in-block LDS reduction,
// coalesced atomics across grid.y.

typedef float v2f __attribute__((ext_vector_type(2)));
typedef float v4f __attribute__((ext_vector_type(4)));

#define BLK 256
#define NS 4            // waves per block = in-block n-splits
#define QPT 4           // queries per lane = 2 packed groups
#define QPB 256         // queries per block = 64 * QPT
#define JCHUNK 128      // j per block
#define JW (JCHUNK / NS)

static __device__ __forceinline__ v2f vbc(float s) { return (v2f){s, s}; }

__global__ __launch_bounds__(BLK, 4) void tps_kernel(
    const float* __restrict__ u,     // (batch, 3)
    const float* __restrict__ cp,    // (n, 3)
    const float* __restrict__ w,     // (n, 3)
    const float* __restrict__ poly,  // (4, 3)
    float* __restrict__ out,         // (batch, 3)
    int batch, int n)
{
    // Pre-duplicated packed records, 2 x v4f per j each:
    //   s_a4[2j]   = {-2cx,-2cx,-2cy,-2cy}   s_a4[2j+1] = {-2cz,-2cz,c2,c2}
    //   s_b4[2j]   = {Cwx,Cwx,Cwy,Cwy}       s_b4[2j+1] = {Cwz,Cwz,0,0}
    __shared__ v4f s_a4[JCHUNK * 2];
    __shared__ v4f s_b4[JCHUNK * 2];
    __shared__ float s_red[NS][QPB * 3];   // per-wave partials (12 KB)

    const float C = 0.34657359027997264f;  // 0.5 * ln(2)

    const int tid = threadIdx.x;
    const int j0 = blockIdx.y * JCHUNK;

    if (tid < JCHUNK) {  // stage + transform + duplicate this 128-j slice
        const int g = j0 + tid;
        const float cx = cp[g * 3 + 0], cy = cp[g * 3 + 1], cz = cp[g * 3 + 2];
        const float c2 = fmaf(cx, cx, fmaf(cy, cy, cz * cz));
        const float wx = C * w[g * 3 + 0];
        const float wy = C * w[g * 3 + 1];
        const float wz = C * w[g * 3 + 2];
        s_a4[tid * 2 + 0] = (v4f){-2.f * cx, -2.f * cx, -2.f * cy, -2.f * cy};
        s_a4[tid * 2 + 1] = (v4f){-2.f * cz, -2.f * cz, c2, c2};
        s_b4[tid * 2 + 0] = (v4f){wx, wx, wy, wy};
        s_b4[tid * 2 + 1] = (v4f){wz, wz, 0.f, 0.f};
    }
    __syncthreads();

    const int lane = tid & 63;
    const int wv   = tid >> 6;    // 0..3 = n-split

    // 2 packed groups: group g holds queries (2g)*64+lane and (2g+1)*64+lane
    v2f uxv[2], uyv[2], uzv[2], usqv[2];
    v2f axv[2], ayv[2], azv[2];
#pragma unroll
    for (int g = 0; g < 2; ++g) {
        const int qa = blockIdx.x * QPB + (2 * g + 0) * 64 + lane;
        const int qb = blockIdx.x * QPB + (2 * g + 1) * 64 + lane;
        uxv[g] = (v2f){u[qa * 3 + 0], u[qb * 3 + 0]};
        uyv[g] = (v2f){u[qa * 3 + 1], u[qb * 3 + 1]};
        uzv[g] = (v2f){u[qa * 3 + 2], u[qb * 3 + 2]};
        usqv[g] = __builtin_elementwise_fma(uxv[g], uxv[g],
                  __builtin_elementwise_fma(uyv[g], uyv[g], uzv[g] * uzv[g]));
        axv[g] = (v2f){0.f, 0.f};
        ayv[g] = (v2f){0.f, 0.f};
        azv[g] = (v2f){0.f, 0.f};
    }

    if (blockIdx.y == 0 && wv == 0) {  // polynomial term exactly once
#pragma unroll
        for (int g = 0; g < 2; ++g) {
            axv[g] = poly[0] + uxv[g] * poly[3] + uyv[g] * poly[6] + uzv[g] * poly[9];
            ayv[g] = poly[1] + uxv[g] * poly[4] + uyv[g] * poly[7] + uzv[g] * poly[10];
            azv[g] = poly[2] + uxv[g] * poly[5] + uyv[g] * poly[8] + uzv[g] * poly[11];
        }
    }

    // h(t) = log2(1+t) - t on [0,1): degree-6, Chebyshev-truncation derived
    // (max err ~3e-6 in log2). log2(r2) = z + h(t), z = e + t exact.
    const float H1 =  0.44247503f;
    const float H2 = -0.71755682f;
    const float H3 =  0.45552900f;
    const float H4 = -0.27463104f;
    const float H5 =  0.11930607f;
    const float H6 = -0.02512566f;

    const int jlo = wv * JW;
#pragma unroll 2
    for (int j = jlo; j < jlo + JW; ++j) {
        const v4f A0 = s_a4[j * 2 + 0];  // {ax,ax,ay,ay}
        const v4f A1 = s_a4[j * 2 + 1];  // {az,az,c2,c2}
        const v4f B0 = s_b4[j * 2 + 0];  // {wx,wx,wy,wy}
        const v4f B1 = s_b4[j * 2 + 1];  // {wz,wz,0,0}
        const v2f m2x = A0.xy, m2y = A0.zw, m2z = A1.xy, c2v = A1.zw;
        const v2f wxv = B0.xy, wyv = B0.zw, wzv = B1.xy;
#pragma unroll
        for (int g = 0; g < 2; ++g) {
            v2f r2 = __builtin_elementwise_fma(m2x, uxv[g],
                     __builtin_elementwise_fma(m2y, uyv[g],
                     __builtin_elementwise_fma(m2z, uzv[g], c2v + usqv[g])));
            r2 = __builtin_elementwise_max(r2, vbc(1e-30f));

            const unsigned bx = __float_as_uint(r2.x);
            const unsigned by = __float_as_uint(r2.y);

            // ---- sqrt(r2): magic rsqrt seed + 2 packed Newton, sq = r2*x
            v2f x = (v2f){__uint_as_float(0x5f3759dfu - (bx >> 1)),
                          __uint_as_float(0x5f3759dfu - (by >> 1))};
            const v2f r2h = r2 * 0.5f;
            v2f xx = x * x;
            x = x * __builtin_elementwise_fma(-r2h, xx, vbc(1.5f));
            xx = x * x;
            x = x * __builtin_elementwise_fma(-r2h, xx, vbc(1.5f));
            const v2f sq = r2 * x;

            // ---- log2(r2): z = float(bits)*2^-23 - 127 = e + t (exact),
            //      lg = z + h(t) with t = mantissa - 1
            const v2f bf = (v2f){(float)bx, (float)by};
            const v2f z  = __builtin_elementwise_fma(bf, vbc(0x1p-23f), vbc(-127.0f));
            const v2f mf = (v2f){__uint_as_float((bx & 0x7fffffu) | 0x3f800000u),
                                 __uint_as_float((by & 0x7fffffu) | 0x3f800000u)};
            const v2f t = mf - 1.0f;
            v2f p = vbc(H6);
            p = __builtin_elementwise_fma(p, t, vbc(H5));
            p = __builtin_elementwise_fma(p, t, vbc(H4));
            p = __builtin_elementwise_fma(p, t, vbc(H3));
            p = __builtin_elementwise_fma(p, t, vbc(H2));
            p = __builtin_elementwise_fma(p, t, vbc(H1));
            const v2f lg = __builtin_elementwise_fma(p, t, z);

            const v2f kk = sq * lg;      // * C folded into staged weights
            axv[g] = __builtin_elementwise_fma(kk, wxv, axv[g]);
            ayv[g] = __builtin_elementwise_fma(kk, wyv, ayv[g]);
            azv[g] = __builtin_elementwise_fma(kk, wzv, azv[g]);
        }
    }

    // In-block reduction across the 4 n-split waves.
#pragma unroll
    for (int g = 0; g < 2; ++g) {
        const int ba = ((2 * g + 0) * 64 + lane) * 3;
        const int bb = ((2 * g + 1) * 64 + lane) * 3;
        s_red[wv][ba + 0] = axv[g].x;  s_red[wv][bb + 0] = axv[g].y;
        s_red[wv][ba + 1] = ayv[g].x;  s_red[wv][bb + 1] = ayv[g].y;
        s_red[wv][ba + 2] = azv[g].x;  s_red[wv][bb + 2] = azv[g].y;
    }
    __syncthreads();

    for (int v = tid; v < QPB * 3; v += BLK) {
        float s = s_red[0][v] + s_red[1][v] + s_red[2][v] + s_red[3][v];
        atomicAdd(&out[(size_t)blockIdx.x * (QPB * 3) + v], s);
    }
}

extern "C" void kernel_launch(void* const* d_in, const int* in_sizes, int n_in,
                              void* d_out, int out_size, void* d_ws, size_t ws_size,
                              hipStream_t stream) {
    const float* u    = (const float*)d_in[0];  // (batch,3)
    const float* cp   = (const float*)d_in[1];  // (n,3)
    const float* w    = (const float*)d_in[2];  // (n,3)
    const float* poly = (const float*)d_in[3];  // (4,3)
    float* out = (float*)d_out;

    const int batch = in_sizes[0] / 3;  // 16384
    const int n     = in_sizes[1] / 3;  // 4096

    hipMemsetAsync(d_out, 0, (size_t)out_size * sizeof(float), stream);

    dim3 block(BLK);
    dim3 grid(batch / QPB, n / JCHUNK);  // (64, 32) = 2048 blocks
    tps_kernel<<<grid, block, 0, stream>>>(u, cp, w, poly, out, batch, n);
}

// Round 2
// 88.206 us; speedup vs baseline: 1.0614x; 1.0614x over previous
//
#include <hip/hip_runtime.h>

// ThinPlateSpline: out = K_query @ rbf_weights + P_query @ poly_coeffs
//   K_ij = r*ln(r), r = ||u_i - c_j|| (d=3)
//   kk = sqrt(r2) * log2(r2) * C, C = 0.5*ln2 folded into staged weights.
//
// R15: pipe-split hybrid. R13 (both ops on trans pipe) = 33us trans-bound;
// R14 (both ops on VALU as polynomials) = 43us VALU-bound with trans idle
// (VALU-busy 29us ~= 2x static count -> packed ops cost ~2x, chains stall).
// Optimum is the split:
//   sqrt:  hardware v_sqrt_f32 (trans pipe) -- 2/group, half of R13's trans
//          load, and removes the 12-instr magic-Newton block from VALU.
//   log2:  exponent float-hack + deg-6 poly h(t)=log2(1+t)-t (VALU pipe,
//          ~15 instrs/group incl cvt/and_or).
// VALU/group: 33 -> 21; trans/group: 0 -> 2 (vs R13's 4). Both pipes ~9-18us
// and overlap. Predicted kernel ~18-24us, bench ~65-70us, absmax <=0.25.
// Structure = R13/R14: BLK=256 (4 waves = 4 n-splits), JCHUNK=128, grid
// (64,32) = 2048 blocks, pre-duplicated packed LDS records, in-block LDS
// reduction, coalesced atomics across grid.y.

typedef float v2f __attribute__((ext_vector_type(2)));
typedef float v4f __attribute__((ext_vector_type(4)));

#define BLK 256
#define NS 4            // waves per block = in-block n-splits
#define QPT 4           // queries per lane = 2 packed groups
#define QPB 256         // queries per block = 64 * QPT
#define JCHUNK 128      // j per block
#define JW (JCHUNK / NS)

static __device__ __forceinline__ v2f vbc(float s) { return (v2f){s, s}; }

__global__ __launch_bounds__(BLK, 8) void tps_kernel(
    const float* __restrict__ u,     // (batch, 3)
    const float* __restrict__ cp,    // (n, 3)
    const float* __restrict__ w,     // (n, 3)
    const float* __restrict__ poly,  // (4, 3)
    float* __restrict__ out,         // (batch, 3)
    int batch, int n)
{
    // Pre-duplicated packed records, 2 x v4f per j each:
    //   s_a4[2j]   = {-2cx,-2cx,-2cy,-2cy}   s_a4[2j+1] = {-2cz,-2cz,c2,c2}
    //   s_b4[2j]   = {Cwx,Cwx,Cwy,Cwy}       s_b4[2j+1] = {Cwz,Cwz,0,0}
    __shared__ v4f s_a4[JCHUNK * 2];
    __shared__ v4f s_b4[JCHUNK * 2];
    __shared__ float s_red[NS][QPB * 3];   // per-wave partials (12 KB)

    const float C = 0.34657359027997264f;  // 0.5 * ln(2)

    const int tid = threadIdx.x;
    const int j0 = blockIdx.y * JCHUNK;

    if (tid < JCHUNK) {  // stage + transform + duplicate this 128-j slice
        const int g = j0 + tid;
        const float cx = cp[g * 3 + 0], cy = cp[g * 3 + 1], cz = cp[g * 3 + 2];
        const float c2 = fmaf(cx, cx, fmaf(cy, cy, cz * cz));
        const float wx = C * w[g * 3 + 0];
        const float wy = C * w[g * 3 + 1];
        const float wz = C * w[g * 3 + 2];
        s_a4[tid * 2 + 0] = (v4f){-2.f * cx, -2.f * cx, -2.f * cy, -2.f * cy};
        s_a4[tid * 2 + 1] = (v4f){-2.f * cz, -2.f * cz, c2, c2};
        s_b4[tid * 2 + 0] = (v4f){wx, wx, wy, wy};
        s_b4[tid * 2 + 1] = (v4f){wz, wz, 0.f, 0.f};
    }
    __syncthreads();

    const int lane = tid & 63;
    const int wv   = tid >> 6;    // 0..3 = n-split

    // 2 packed groups: group g holds queries (2g)*64+lane and (2g+1)*64+lane
    v2f uxv[2], uyv[2], uzv[2], usqv[2];
    v2f axv[2], ayv[2], azv[2];
#pragma unroll
    for (int g = 0; g < 2; ++g) {
        const int qa = blockIdx.x * QPB + (2 * g + 0) * 64 + lane;
        const int qb = blockIdx.x * QPB + (2 * g + 1) * 64 + lane;
        uxv[g] = (v2f){u[qa * 3 + 0], u[qb * 3 + 0]};
        uyv[g] = (v2f){u[qa * 3 + 1], u[qb * 3 + 1]};
        uzv[g] = (v2f){u[qa * 3 + 2], u[qb * 3 + 2]};
        usqv[g] = __builtin_elementwise_fma(uxv[g], uxv[g],
                  __builtin_elementwise_fma(uyv[g], uyv[g], uzv[g] * uzv[g]));
        axv[g] = (v2f){0.f, 0.f};
        ayv[g] = (v2f){0.f, 0.f};
        azv[g] = (v2f){0.f, 0.f};
    }

    if (blockIdx.y == 0 && wv == 0) {  // polynomial term exactly once
#pragma unroll
        for (int g = 0; g < 2; ++g) {
            axv[g] = poly[0] + uxv[g] * poly[3] + uyv[g] * poly[6] + uzv[g] * poly[9];
            ayv[g] = poly[1] + uxv[g] * poly[4] + uyv[g] * poly[7] + uzv[g] * poly[10];
            azv[g] = poly[2] + uxv[g] * poly[5] + uyv[g] * poly[8] + uzv[g] * poly[11];
        }
    }

    // h(t) = log2(1+t) - t on [0,1): degree-6, Chebyshev-truncation derived
    // (max err ~3e-6 in log2). log2(r2) = z + h(t), z = e + t exact
    // where z = float(bits)*2^-23 - 127.
    const float H1 =  0.44247503f;
    const float H2 = -0.71755682f;
    const float H3 =  0.45552900f;
    const float H4 = -0.27463104f;
    const float H5 =  0.11930607f;
    const float H6 = -0.02512566f;

    const int jlo = wv * JW;
#pragma unroll 2
    for (int j = jlo; j < jlo + JW; ++j) {
        const v4f A0 = s_a4[j * 2 + 0];  // {ax,ax,ay,ay}
        const v4f A1 = s_a4[j * 2 + 1];  // {az,az,c2,c2}
        const v4f B0 = s_b4[j * 2 + 0];  // {wx,wx,wy,wy}
        const v4f B1 = s_b4[j * 2 + 1];  // {wz,wz,0,0}
        const v2f m2x = A0.xy, m2y = A0.zw, m2z = A1.xy, c2v = A1.zw;
        const v2f wxv = B0.xy, wyv = B0.zw, wzv = B1.xy;
#pragma unroll
        for (int g = 0; g < 2; ++g) {
            v2f r2 = __builtin_elementwise_fma(m2x, uxv[g],
                     __builtin_elementwise_fma(m2y, uyv[g],
                     __builtin_elementwise_fma(m2z, uzv[g], c2v + usqv[g])));
            r2 = __builtin_elementwise_max(r2, vbc(1e-30f));

            // ---- sqrt(r2): hardware trans pipe (overlaps with VALU poly)
            const v2f sq = {__builtin_amdgcn_sqrtf(r2.x),
                            __builtin_amdgcn_sqrtf(r2.y)};

            // ---- log2(r2) on VALU: z = float(bits)*2^-23 - 127 = e + t
            //      (exact), lg = z + h(t) with t = mantissa - 1
            const unsigned bx = __float_as_uint(r2.x);
            const unsigned by = __float_as_uint(r2.y);
            const v2f bf = (v2f){(float)bx, (float)by};
            const v2f z  = __builtin_elementwise_fma(bf, vbc(0x1p-23f), vbc(-127.0f));
            const v2f mf = (v2f){__uint_as_float((bx & 0x7fffffu) | 0x3f800000u),
                                 __uint_as_float((by & 0x7fffffu) | 0x3f800000u)};
            const v2f t = mf - 1.0f;
            v2f p = vbc(H6);
            p = __builtin_elementwise_fma(p, t, vbc(H5));
            p = __builtin_elementwise_fma(p, t, vbc(H4));
            p = __builtin_elementwise_fma(p, t, vbc(H3));
            p = __builtin_elementwise_fma(p, t, vbc(H2));
            p = __builtin_elementwise_fma(p, t, vbc(H1));
            const v2f lg = __builtin_elementwise_fma(p, t, z);

            const v2f kk = sq * lg;      // * C folded into staged weights
            axv[g] = __builtin_elementwise_fma(kk, wxv, axv[g]);
            ayv[g] = __builtin_elementwise_fma(kk, wyv, ayv[g]);
            azv[g] = __builtin_elementwise_fma(kk, wzv, azv[g]);
        }
    }

    // In-block reduction across the 4 n-split waves.
#pragma unroll
    for (int g = 0; g < 2; ++g) {
        const int ba = ((2 * g + 0) * 64 + lane) * 3;
        const int bb = ((2 * g + 1) * 64 + lane) * 3;
        s_red[wv][ba + 0] = axv[g].x;  s_red[wv][bb + 0] = axv[g].y;
        s_red[wv][ba + 1] = ayv[g].x;  s_red[wv][bb + 1] = ayv[g].y;
        s_red[wv][ba + 2] = azv[g].x;  s_red[wv][bb + 2] = azv[g].y;
    }
    __syncthreads();

    for (int v = tid; v < QPB * 3; v += BLK) {
        float s = s_red[0][v] + s_red[1][v] + s_red[2][v] + s_red[3][v];
        atomicAdd(&out[(size_t)blockIdx.x * (QPB * 3) + v], s);
    }
}

extern "C" void kernel_launch(void* const* d_in, const int* in_sizes, int n_in,
                              void* d_out, int out_size, void* d_ws, size_t ws_size,
                              hipStream_t stream) {
    const float* u    = (const float*)d_in[0];  // (batch,3)
    const float* cp   = (const float*)d_in[1];  // (n,3)
    const float* w    = (const float*)d_in[2];  // (n,3)
    const float* poly = (const float*)d_in[3];  // (4,3)
    float* out = (float*)d_out;

    const int batch = in_sizes[0] / 3;  // 16384
    const int n     = in_sizes[1] / 3;  // 4096

    hipMemsetAsync(d_out, 0, (size_t)out_size * sizeof(float), stream);

    dim3 block(BLK);
    dim3 grid(batch / QPB, n / JCHUNK);  // (64, 32) = 2048 blocks
    tps_kernel<<<grid, block, 0, stream>>>(u, cp, w, poly, out, batch, n);
}